// Round 1
// baseline (575.339 us; speedup 1.0000x reference)
//
#include <hip/hip_runtime.h>
#include <math.h>

// Problem constants
#define NB 8
#define NN 256
#define ND 64
#define NE 64
#define NR 32
// mu_r = 20*r/31, sigma = 20/32 = 0.625, 1/sigma = 1.6

__device__ __forceinline__ float rl(float x, int lane) {
    return __uint_as_float(__builtin_amdgcn_readlane(__float_as_uint(x), lane));
}

__device__ __forceinline__ float wave_sum64(float v) {
#pragma unroll
    for (int m = 32; m >= 1; m >>= 1) v += __shfl_xor(v, m, 64);
    return v;
}

// -------- K1: node = LN(relu(emb[atom]) @ ne_w + ne_b); s' = node@Ws + b1; t = node@Wt
__global__ __launch_bounds__(256) void k1_node(
    const int* __restrict__ atom, const float* __restrict__ emb,
    const float* __restrict__ ne_w, const float* __restrict__ ne_b,
    const float* __restrict__ ne_g, const float* __restrict__ ne_beta,
    const float* __restrict__ ee_w1, const float* __restrict__ ee_b1,
    float* __restrict__ ws_node, float* __restrict__ ws_s, float* __restrict__ ws_t)
{
    const int wave = threadIdx.x >> 6;
    const int lane = threadIdx.x & 63;
    const int row  = blockIdx.x * 4 + wave;          // b*N + n, < 2048

    const int a = atom[row];
    float ev = fmaxf(emb[a * ND + lane], 0.f);

    float a0 = 0.f, a1 = 0.f, a2 = 0.f, a3 = 0.f;
#pragma unroll
    for (int k = 0; k < ND; k += 4) {
        a0 = fmaf(rl(ev, k + 0), ne_w[(k + 0) * ND + lane], a0);
        a1 = fmaf(rl(ev, k + 1), ne_w[(k + 1) * ND + lane], a1);
        a2 = fmaf(rl(ev, k + 2), ne_w[(k + 2) * ND + lane], a2);
        a3 = fmaf(rl(ev, k + 3), ne_w[(k + 3) * ND + lane], a3);
    }
    float pre = ne_b[lane] + ((a0 + a1) + (a2 + a3));

    float mean = wave_sum64(pre) * (1.f / 64.f);
    float dv = pre - mean;
    float var = wave_sum64(dv * dv) * (1.f / 64.f);
    float nv = dv * rsqrtf(var + 1e-5f) * ne_g[lane] + ne_beta[lane];
    ws_node[row * ND + lane] = nv;

    // s' = node @ Ws + b1 (Ws = ee_w1 rows [0,64)), t = node @ Wt (rows [64,128))
    float s0 = 0.f, s1 = 0.f, t0 = 0.f, t1 = 0.f;
#pragma unroll
    for (int k = 0; k < ND; k += 2) {
        float n0 = rl(nv, k), n1 = rl(nv, k + 1);
        s0 = fmaf(n0, ee_w1[(k)     * NE + lane], s0);
        s1 = fmaf(n1, ee_w1[(k + 1) * NE + lane], s1);
        t0 = fmaf(n0, ee_w1[(ND + k)     * NE + lane], t0);
        t1 = fmaf(n1, ee_w1[(ND + k + 1) * NE + lane], t1);
    }
    ws_s[row * NE + lane] = ee_b1[lane] + s0 + s1;
    ws_t[row * NE + lane] = t0 + t1;
}

// -------- K2: per (b,j) block; 4 waves loop over i; compute edge + agg
__global__ __launch_bounds__(256, 2) void k2_edge(
    const float* __restrict__ pos, const float* __restrict__ mask,
    const int* __restrict__ atom,
    const float* __restrict__ ee_w1,
    const float* __restrict__ ee_w2, const float* __restrict__ ee_b2,
    const float* __restrict__ ee_w3, const float* __restrict__ ee_b3,
    const float* __restrict__ ee_g, const float* __restrict__ ee_beta,
    const float* __restrict__ ws_s, const float* __restrict__ ws_t,
    float* __restrict__ edge_out, float* __restrict__ ws_agg)
{
    const int bj = blockIdx.x;                 // b*N + j
    const int b = bj >> 8, j = bj & 255;
    const int wave = threadIdx.x >> 6, lane = threadIdx.x & 63;

    // weight columns in registers (col = lane)
    float wr[NR], w2c[ND], w3c[ND];
#pragma unroll
    for (int r = 0; r < NR; r++) wr[r] = ee_w1[(2 * ND + r) * NE + lane];
#pragma unroll
    for (int k = 0; k < ND; k++) w2c[k] = ee_w2[k * NE + lane];
#pragma unroll
    for (int k = 0; k < ND; k++) w3c[k] = ee_w3[k * NE + lane];

    const float b2e = ee_b2[lane], b3e = ee_b3[lane];
    const float ge = ee_g[lane], be = ee_beta[lane];

    const float sje = ws_s[bj * NE + lane];    // s'(b,j,e) incl. b1
    const float pjx = pos[bj * 3 + 0], pjy = pos[bj * 3 + 1], pjz = pos[bj * 3 + 2];
    const float mur = (20.f / 31.f) * (float)(lane & 31);

    float agg_acc = 0.f;
    float msum = 0.f;

    for (int ii = 0; ii < 64; ii++) {
        const int i = wave + 4 * ii;
        const int bi = (b << 8) + i;
        const float tie = ws_t[bi * NE + lane];
        const float m = mask[(bi) * NN + j];   // mask[b][i][j]
        const float dx = pjx - pos[bi * 3 + 0];
        const float dy = pjy - pos[bi * 3 + 1];
        const float dz = pjz - pos[bi * 3 + 2];
        const float dist = sqrtf(fmaf(dx, dx, fmaf(dy, dy, fmaf(dz, dz, 1e-10f)))) * m;
        const float u = (dist - mur) * 1.6f;
        const float rv = __expf(-u * u) * m;   // rbf[r = lane&31]

        // pre1 = s' + t + sum_r rbf[r]*Wr[r][e]
        float c0 = sje + tie, c1 = 0.f, c2 = 0.f, c3 = 0.f;
#pragma unroll
        for (int r = 0; r < NR; r += 4) {
            c0 = fmaf(rl(rv, r + 0), wr[r + 0], c0);
            c1 = fmaf(rl(rv, r + 1), wr[r + 1], c1);
            c2 = fmaf(rl(rv, r + 2), wr[r + 2], c2);
            c3 = fmaf(rl(rv, r + 3), wr[r + 3], c3);
        }
        const float h1 = fmaxf((c0 + c1) + (c2 + c3), 0.f);

        float d0 = b2e, d1 = 0.f, d2 = 0.f, d3 = 0.f;
#pragma unroll
        for (int k = 0; k < ND; k += 4) {
            d0 = fmaf(rl(h1, k + 0), w2c[k + 0], d0);
            d1 = fmaf(rl(h1, k + 1), w2c[k + 1], d1);
            d2 = fmaf(rl(h1, k + 2), w2c[k + 2], d2);
            d3 = fmaf(rl(h1, k + 3), w2c[k + 3], d3);
        }
        const float h2 = fmaxf((d0 + d1) + (d2 + d3), 0.f);

        float e0 = b3e, e1 = 0.f, e2 = 0.f, e3 = 0.f;
#pragma unroll
        for (int k = 0; k < ND; k += 4) {
            e0 = fmaf(rl(h2, k + 0), w3c[k + 0], e0);
            e1 = fmaf(rl(h2, k + 1), w3c[k + 1], e1);
            e2 = fmaf(rl(h2, k + 2), w3c[k + 2], e2);
            e3 = fmaf(rl(h2, k + 3), w3c[k + 3], e3);
        }
        const float p3 = (e0 + e1) + (e2 + e3);

        const float mean = wave_sum64(p3) * (1.f / 64.f);
        const float dvv = p3 - mean;
        const float var = wave_sum64(dvv * dvv) * (1.f / 64.f);
        const float y = dvv * rsqrtf(var + 1e-5f) * ge + be;

        edge_out[((size_t)bi * NN + j) * NE + lane] = y;
        agg_acc += y;
        msum += m;
    }

    __shared__ float part[4][64];
    __shared__ float mpart[4];
    part[wave][lane] = agg_acc;
    if (lane == 0) mpart[wave] = msum;
    __syncthreads();
    if (wave == 0) {
        const float tot = part[0][lane] + part[1][lane] + part[2][lane] + part[3][lane];
        const float mt = mpart[0] + mpart[1] + mpart[2] + mpart[3];
        const float gate = (atom[bj] > 0) ? 1.f : 0.f;  // min(atom,1), atom >= 0
        ws_agg[bj * NE + lane] = tot / (mt + 1e-10f) * gate;
    }
}

// -------- K3: x = MLP(concat(node, agg)); out0 = node + LN-output
__global__ __launch_bounds__(256) void k3_final(
    const float* __restrict__ ws_node, const float* __restrict__ ws_agg,
    const float* __restrict__ na_w1, const float* __restrict__ na_b1,
    const float* __restrict__ na_w2, const float* __restrict__ na_b2,
    const float* __restrict__ na_w3, const float* __restrict__ na_b3,
    const float* __restrict__ na_g, const float* __restrict__ na_beta,
    float* __restrict__ out0)
{
    const int wave = threadIdx.x >> 6;
    const int lane = threadIdx.x & 63;
    const int row = blockIdx.x * 4 + wave;

    const float nv = ws_node[row * ND + lane];
    const float av = ws_agg[row * ND + lane];

    float a0 = 0.f, a1 = 0.f, a2 = 0.f, a3 = 0.f;
#pragma unroll
    for (int k = 0; k < ND; k += 2) {
        a0 = fmaf(rl(nv, k),     na_w1[(k)     * ND + lane], a0);
        a1 = fmaf(rl(nv, k + 1), na_w1[(k + 1) * ND + lane], a1);
        a2 = fmaf(rl(av, k),     na_w1[(ND + k)     * ND + lane], a2);
        a3 = fmaf(rl(av, k + 1), na_w1[(ND + k + 1) * ND + lane], a3);
    }
    const float x1 = fmaxf(na_b1[lane] + (a0 + a1) + (a2 + a3), 0.f);

    float b0 = 0.f, b1 = 0.f, b2 = 0.f, b3 = 0.f;
#pragma unroll
    for (int k = 0; k < ND; k += 4) {
        b0 = fmaf(rl(x1, k + 0), na_w2[(k + 0) * ND + lane], b0);
        b1 = fmaf(rl(x1, k + 1), na_w2[(k + 1) * ND + lane], b1);
        b2 = fmaf(rl(x1, k + 2), na_w2[(k + 2) * ND + lane], b2);
        b3 = fmaf(rl(x1, k + 3), na_w2[(k + 3) * ND + lane], b3);
    }
    const float x2 = fmaxf(na_b2[lane] + (b0 + b1) + (b2 + b3), 0.f);

    float c0 = 0.f, c1 = 0.f, c2 = 0.f, c3 = 0.f;
#pragma unroll
    for (int k = 0; k < ND; k += 4) {
        c0 = fmaf(rl(x2, k + 0), na_w3[(k + 0) * ND + lane], c0);
        c1 = fmaf(rl(x2, k + 1), na_w3[(k + 1) * ND + lane], c1);
        c2 = fmaf(rl(x2, k + 2), na_w3[(k + 2) * ND + lane], c2);
        c3 = fmaf(rl(x2, k + 3), na_w3[(k + 3) * ND + lane], c3);
    }
    const float p3 = na_b3[lane] + (c0 + c1) + (c2 + c3);

    const float mean = wave_sum64(p3) * (1.f / 64.f);
    const float dvv = p3 - mean;
    const float var = wave_sum64(dvv * dvv) * (1.f / 64.f);
    const float x3 = dvv * rsqrtf(var + 1e-5f) * na_g[lane] + na_beta[lane];

    out0[row * ND + lane] = nv + x3;
}

extern "C" void kernel_launch(void* const* d_in, const int* in_sizes, int n_in,
                              void* d_out, int out_size, void* d_ws, size_t ws_size,
                              hipStream_t stream) {
    const int*   atom    = (const int*)d_in[0];
    const float* pos     = (const float*)d_in[1];
    const float* mask    = (const float*)d_in[2];
    const float* emb     = (const float*)d_in[3];
    const float* ne_w    = (const float*)d_in[4];
    const float* ne_b    = (const float*)d_in[5];
    const float* ne_g    = (const float*)d_in[6];
    const float* ne_beta = (const float*)d_in[7];
    const float* ee_w1   = (const float*)d_in[8];
    const float* ee_b1   = (const float*)d_in[9];
    const float* ee_w2   = (const float*)d_in[10];
    const float* ee_b2   = (const float*)d_in[11];
    const float* ee_w3   = (const float*)d_in[12];
    const float* ee_b3   = (const float*)d_in[13];
    const float* ee_g    = (const float*)d_in[14];
    const float* ee_beta = (const float*)d_in[15];
    const float* na_w1   = (const float*)d_in[16];
    const float* na_b1   = (const float*)d_in[17];
    const float* na_w2   = (const float*)d_in[18];
    const float* na_b2   = (const float*)d_in[19];
    const float* na_w3   = (const float*)d_in[20];
    const float* na_b3   = (const float*)d_in[21];
    const float* na_g    = (const float*)d_in[22];
    const float* na_beta = (const float*)d_in[23];

    float* out0     = (float*)d_out;                       // (B,N,D) = 131072
    float* edge_out = (float*)d_out + NB * NN * ND;        // (B,N,N,E)

    float* ws_node = (float*)d_ws;                         // 131072 floats
    float* ws_s    = ws_node + NB * NN * ND;               // 131072
    float* ws_t    = ws_s + NB * NN * NE;                  // 131072
    float* ws_agg  = ws_t + NB * NN * NE;                  // 131072

    hipLaunchKernelGGL(k1_node, dim3(NB * NN / 4), dim3(256), 0, stream,
                       atom, emb, ne_w, ne_b, ne_g, ne_beta, ee_w1, ee_b1,
                       ws_node, ws_s, ws_t);

    hipLaunchKernelGGL(k2_edge, dim3(NB * NN), dim3(256), 0, stream,
                       pos, mask, atom, ee_w1, ee_w2, ee_b2, ee_w3, ee_b3,
                       ee_g, ee_beta, ws_s, ws_t, edge_out, ws_agg);

    hipLaunchKernelGGL(k3_final, dim3(NB * NN / 4), dim3(256), 0, stream,
                       ws_node, ws_agg, na_w1, na_b1, na_w2, na_b2, na_w3, na_b3,
                       na_g, na_beta, out0);
}

// Round 2
// 248.465 us; speedup vs baseline: 2.3156x; 2.3156x over previous
//
#include <hip/hip_runtime.h>
#include <math.h>

// Problem constants
#define NB 8
#define NN 256
#define ND 64
#define NE 64
#define NR 32
// mu_r = 20*r/31, sigma = 0.625, 1/sigma = 1.6

typedef short short8 __attribute__((ext_vector_type(8)));
typedef float f32x4 __attribute__((ext_vector_type(4)));

__device__ __forceinline__ unsigned short f2bf(float f) {
    unsigned int u = __float_as_uint(f);
    u += 0x7fffu + ((u >> 16) & 1u);   // round-to-nearest-even
    return (unsigned short)(u >> 16);
}

__device__ __forceinline__ float rl(float x, int lane) {
    return __uint_as_float(__builtin_amdgcn_readlane(__float_as_uint(x), lane));
}

__device__ __forceinline__ float wave_sum64(float v) {
#pragma unroll
    for (int m = 32; m >= 1; m >>= 1) v += __shfl_xor(v, m, 64);
    return v;
}

// -------- prep: bf16 transposed weight copies for MFMA B-fragments ([n][k] layout)
__global__ __launch_bounds__(256) void k_prep(
    const float* __restrict__ ee_w1, const float* __restrict__ ee_w2,
    const float* __restrict__ ee_w3,
    unsigned short* __restrict__ wr_t, unsigned short* __restrict__ w2t,
    unsigned short* __restrict__ w3t)
{
    const int t = threadIdx.x;
    for (int idx = t; idx < NE * NR; idx += 256) {      // wr_t[e][r]
        int e = idx >> 5, r = idx & 31;
        wr_t[idx] = f2bf(ee_w1[(2 * ND + r) * NE + e]);
    }
    for (int idx = t; idx < NE * NE; idx += 256) {      // w2t[n][k]
        int n = idx >> 6, k = idx & 63;
        w2t[idx] = f2bf(ee_w2[k * NE + n]);
        w3t[idx] = f2bf(ee_w3[k * NE + n]);
    }
}

// -------- K1: node = LN(relu(emb[atom]) @ ne_w + ne_b); s' = node@Ws + b1; t = node@Wt
__global__ __launch_bounds__(256) void k1_node(
    const int* __restrict__ atom, const float* __restrict__ emb,
    const float* __restrict__ ne_w, const float* __restrict__ ne_b,
    const float* __restrict__ ne_g, const float* __restrict__ ne_beta,
    const float* __restrict__ ee_w1, const float* __restrict__ ee_b1,
    float* __restrict__ ws_node, float* __restrict__ ws_s, float* __restrict__ ws_t)
{
    const int wave = threadIdx.x >> 6;
    const int lane = threadIdx.x & 63;
    const int row  = blockIdx.x * 4 + wave;

    const int a = atom[row];
    float ev = fmaxf(emb[a * ND + lane], 0.f);

    float a0 = 0.f, a1 = 0.f, a2 = 0.f, a3 = 0.f;
#pragma unroll
    for (int k = 0; k < ND; k += 4) {
        a0 = fmaf(rl(ev, k + 0), ne_w[(k + 0) * ND + lane], a0);
        a1 = fmaf(rl(ev, k + 1), ne_w[(k + 1) * ND + lane], a1);
        a2 = fmaf(rl(ev, k + 2), ne_w[(k + 2) * ND + lane], a2);
        a3 = fmaf(rl(ev, k + 3), ne_w[(k + 3) * ND + lane], a3);
    }
    float pre = ne_b[lane] + ((a0 + a1) + (a2 + a3));

    float mean = wave_sum64(pre) * (1.f / 64.f);
    float dv = pre - mean;
    float var = wave_sum64(dv * dv) * (1.f / 64.f);
    float nv = dv * rsqrtf(var + 1e-5f) * ne_g[lane] + ne_beta[lane];
    ws_node[row * ND + lane] = nv;

    float s0 = 0.f, s1 = 0.f, t0 = 0.f, t1 = 0.f;
#pragma unroll
    for (int k = 0; k < ND; k += 2) {
        float n0 = rl(nv, k), n1 = rl(nv, k + 1);
        s0 = fmaf(n0, ee_w1[(k)     * NE + lane], s0);
        s1 = fmaf(n1, ee_w1[(k + 1) * NE + lane], s1);
        t0 = fmaf(n0, ee_w1[(ND + k)     * NE + lane], t0);
        t1 = fmaf(n1, ee_w1[(ND + k + 1) * NE + lane], t1);
    }
    ws_s[row * NE + lane] = ee_b1[lane] + s0 + s1;
    ws_t[row * NE + lane] = t0 + t1;
}

// -------- K2 (MFMA): per (b,j) block, wave w owns i-rows [w*64, w*64+64)
// stage1: P1 = RBF @ Wr  (K=32, one mfma/tile), +s[j]+t[i]+b1, relu -> LDS bf16
// stage2: H2 = relu(H1 @ W2 + b2) -> LDS bf16
// stage3: P3 = H2 @ W3 + b3 -> in-register LN -> edge_out + agg partials
__global__ __launch_bounds__(256, 2) void k2_edge(
    const float* __restrict__ pos, const float* __restrict__ mask,
    const int* __restrict__ atom,
    const float* __restrict__ ws_s, const float* __restrict__ ws_t,
    const unsigned short* __restrict__ wr_t, const unsigned short* __restrict__ w2t,
    const unsigned short* __restrict__ w3t,
    const float* __restrict__ ee_b2, const float* __restrict__ ee_b3,
    const float* __restrict__ ee_g, const float* __restrict__ ee_beta,
    float* __restrict__ edge_out, float* __restrict__ ws_agg)
{
    // per-wave private H buffer: 64 rows x 72 bf16 (stride 72 breaks 4-way write conflicts)
    __shared__ unsigned short hbuf[4][64 * 72];
    __shared__ float aggp[4][64];
    __shared__ float mp[4];

    const int bj = blockIdx.x;
    const int b = bj >> 8, j = bj & 255;
    const int wave = threadIdx.x >> 6, lane = threadIdx.x & 63;
    const int quad = lane >> 4, col = lane & 15;
    const int ibase = wave * 64;

    // B-fragments: lane holds B[k = quad*8+jj][n = nt*16+col], 8 contiguous k (transposed bf16 copies)
    short8 wrf[4], w2f[4][2], w3f[4][2];
#pragma unroll
    for (int nt = 0; nt < 4; nt++)
        wrf[nt] = *(const short8*)(wr_t + (nt * 16 + col) * NR + quad * 8);
#pragma unroll
    for (int nt = 0; nt < 4; nt++)
#pragma unroll
        for (int kt = 0; kt < 2; kt++) {
            w2f[nt][kt] = *(const short8*)(w2t + (nt * 16 + col) * NE + kt * 32 + quad * 8);
            w3f[nt][kt] = *(const short8*)(w3t + (nt * 16 + col) * NE + kt * 32 + quad * 8);
        }

    float sj[4], b2v[4], b3v[4], gv[4], bev[4];
#pragma unroll
    for (int nt = 0; nt < 4; nt++) {
        const int e = nt * 16 + col;
        sj[nt]  = ws_s[bj * NE + e];      // includes b1
        b2v[nt] = ee_b2[e];
        b3v[nt] = ee_b3[e];
        gv[nt]  = ee_g[e];
        bev[nt] = ee_beta[e];
    }

    const float pjx = pos[bj * 3 + 0], pjy = pos[bj * 3 + 1], pjz = pos[bj * 3 + 2];

    float murv[8];
#pragma unroll
    for (int t = 0; t < 8; t++) murv[t] = 1.0322580645f * (float)(quad * 8 + t);  // mu_r * 1.6

    // ---- stage 1 A-fragments: rbf computed directly in A layout (m=col, k=quad*8+jj)
    short8 af[4];
    float mrow[4];
#pragma unroll
    for (int mt = 0; mt < 4; mt++) {
        const int i = ibase + mt * 16 + col;
        const int bi = b * NN + i;
        const float m = mask[bi * NN + j];
        const float dx = pjx - pos[bi * 3 + 0];
        const float dy = pjy - pos[bi * 3 + 1];
        const float dz = pjz - pos[bi * 3 + 2];
        const float dist = sqrtf(fmaf(dx, dx, fmaf(dy, dy, fmaf(dz, dz, 1e-10f)))) * m;
        mrow[mt] = m;
        short8 a;
#pragma unroll
        for (int t = 0; t < 8; t++) {
            const float u = fmaf(dist, 1.6f, -murv[t]);
            const float rv = exp2f(u * u * (-1.44269504f)) * m;
            a[t] = (short)f2bf(rv);
        }
        af[mt] = a;
    }

    unsigned short* h = hbuf[wave];

    // ---- stage 1 MFMA: P1 = RBF @ Wr (K=32)
    f32x4 acc[4][4];
#pragma unroll
    for (int mt = 0; mt < 4; mt++)
#pragma unroll
        for (int nt = 0; nt < 4; nt++) {
            f32x4 z = {0.f, 0.f, 0.f, 0.f};
            acc[mt][nt] = __builtin_amdgcn_mfma_f32_16x16x32_bf16(af[mt], wrf[nt], z, 0, 0, 0);
        }

    // epilogue 1: + s[j] + t[i] (+b1 already in s), relu, pack bf16 -> LDS
    {
        const float* tb = ws_t + (b * NN + ibase + quad * 4) * NE + col;
#pragma unroll
        for (int mt = 0; mt < 4; mt++)
#pragma unroll
            for (int nt = 0; nt < 4; nt++)
#pragma unroll
                for (int r = 0; r < 4; r++) {
                    const float tv = tb[(mt * 16 + r) * NE + nt * 16];
                    const float hv = fmaxf(acc[mt][nt][r] + sj[nt] + tv, 0.f);
                    h[(mt * 16 + quad * 4 + r) * 72 + nt * 16 + col] = f2bf(hv);
                }
    }

    // ---- stage 2: H2 = relu(H1 @ W2 + b2)
    short8 a2[4][2];
#pragma unroll
    for (int mt = 0; mt < 4; mt++)
#pragma unroll
        for (int kt = 0; kt < 2; kt++)
            a2[mt][kt] = *(const short8*)(h + (mt * 16 + col) * 72 + kt * 32 + quad * 8);

    f32x4 acc2[4][4];
#pragma unroll
    for (int mt = 0; mt < 4; mt++)
#pragma unroll
        for (int nt = 0; nt < 4; nt++) {
            f32x4 z = {0.f, 0.f, 0.f, 0.f};
            z = __builtin_amdgcn_mfma_f32_16x16x32_bf16(a2[mt][0], w2f[nt][0], z, 0, 0, 0);
            acc2[mt][nt] = __builtin_amdgcn_mfma_f32_16x16x32_bf16(a2[mt][1], w2f[nt][1], z, 0, 0, 0);
        }

#pragma unroll
    for (int mt = 0; mt < 4; mt++)
#pragma unroll
        for (int nt = 0; nt < 4; nt++)
#pragma unroll
            for (int r = 0; r < 4; r++) {
                const float hv = fmaxf(acc2[mt][nt][r] + b2v[nt], 0.f);
                h[(mt * 16 + quad * 4 + r) * 72 + nt * 16 + col] = f2bf(hv);
            }

    // ---- stage 3: P3 = H2 @ W3 + b3
    short8 a3[4][2];
#pragma unroll
    for (int mt = 0; mt < 4; mt++)
#pragma unroll
        for (int kt = 0; kt < 2; kt++)
            a3[mt][kt] = *(const short8*)(h + (mt * 16 + col) * 72 + kt * 32 + quad * 8);

    f32x4 acc3[4][4];
#pragma unroll
    for (int mt = 0; mt < 4; mt++)
#pragma unroll
        for (int nt = 0; nt < 4; nt++) {
            f32x4 z = {0.f, 0.f, 0.f, 0.f};
            z = __builtin_amdgcn_mfma_f32_16x16x32_bf16(a3[mt][0], w3f[nt][0], z, 0, 0, 0);
            acc3[mt][nt] = __builtin_amdgcn_mfma_f32_16x16x32_bf16(a3[mt][1], w3f[nt][1], z, 0, 0, 0);
        }

    // add b3 in place
#pragma unroll
    for (int mt = 0; mt < 4; mt++)
#pragma unroll
        for (int nt = 0; nt < 4; nt++)
#pragma unroll
            for (int r = 0; r < 4; r++)
                acc3[mt][nt][r] += b3v[nt];

    // in-register LN across e (64 cols = 4 nt tiles x 16 lanes of the quad group)
    float meanv[4][4], rsv[4][4];
#pragma unroll
    for (int mt = 0; mt < 4; mt++)
#pragma unroll
        for (int r = 0; r < 4; r++) {
            float s = 0.f, q = 0.f;
#pragma unroll
            for (int nt = 0; nt < 4; nt++) {
                const float x = acc3[mt][nt][r];
                s += x;
                q = fmaf(x, x, q);
            }
#pragma unroll
            for (int m = 1; m <= 8; m <<= 1) {
                s += __shfl_xor(s, m, 64);
                q += __shfl_xor(q, m, 64);
            }
            const float mean = s * (1.f / 64.f);
            const float var = q * (1.f / 64.f) - mean * mean;
            meanv[mt][r] = mean;
            rsv[mt][r] = rsqrtf(var + 1e-5f);
        }

    // write edge + accumulate per-column partial sums for agg
    float ag[4] = {0.f, 0.f, 0.f, 0.f};
    float* eb = edge_out + ((size_t)(b * NN + ibase + quad * 4) * NN + j) * NE + col;
#pragma unroll
    for (int mt = 0; mt < 4; mt++)
#pragma unroll
        for (int nt = 0; nt < 4; nt++)
#pragma unroll
            for (int r = 0; r < 4; r++) {
                const float d = (acc3[mt][nt][r] - meanv[mt][r]) * rsv[mt][r];
                const float y = fmaf(d, gv[nt], bev[nt]);
                eb[(mt * 16 + r) * NN * NE + nt * 16] = y;
                ag[nt] += y;
            }

#pragma unroll
    for (int nt = 0; nt < 4; nt++) {
        ag[nt] += __shfl_xor(ag[nt], 16, 64);
        ag[nt] += __shfl_xor(ag[nt], 32, 64);
    }
    if (quad == 0) {
#pragma unroll
        for (int nt = 0; nt < 4; nt++) aggp[wave][nt * 16 + col] = ag[nt];
    }
    float msu = mrow[0] + mrow[1] + mrow[2] + mrow[3];
#pragma unroll
    for (int m = 1; m <= 8; m <<= 1) msu += __shfl_xor(msu, m, 64);
    if (lane == 0) mp[wave] = msu;

    __syncthreads();
    if (threadIdx.x < 64) {
        const int e = threadIdx.x;
        const float tot = aggp[0][e] + aggp[1][e] + aggp[2][e] + aggp[3][e];
        const float ms = mp[0] + mp[1] + mp[2] + mp[3];
        const float gate = (atom[bj] > 0) ? 1.f : 0.f;
        ws_agg[bj * NE + e] = tot / (ms + 1e-10f) * gate;
    }
}

// -------- K3: x = MLP(concat(node, agg)); out0 = node + LN(x)
__global__ __launch_bounds__(256) void k3_final(
    const float* __restrict__ ws_node, const float* __restrict__ ws_agg,
    const float* __restrict__ na_w1, const float* __restrict__ na_b1,
    const float* __restrict__ na_w2, const float* __restrict__ na_b2,
    const float* __restrict__ na_w3, const float* __restrict__ na_b3,
    const float* __restrict__ na_g, const float* __restrict__ na_beta,
    float* __restrict__ out0)
{
    const int wave = threadIdx.x >> 6;
    const int lane = threadIdx.x & 63;
    const int row = blockIdx.x * 4 + wave;

    const float nv = ws_node[row * ND + lane];
    const float av = ws_agg[row * ND + lane];

    float a0 = 0.f, a1 = 0.f, a2 = 0.f, a3 = 0.f;
#pragma unroll
    for (int k = 0; k < ND; k += 2) {
        a0 = fmaf(rl(nv, k),     na_w1[(k)     * ND + lane], a0);
        a1 = fmaf(rl(nv, k + 1), na_w1[(k + 1) * ND + lane], a1);
        a2 = fmaf(rl(av, k),     na_w1[(ND + k)     * ND + lane], a2);
        a3 = fmaf(rl(av, k + 1), na_w1[(ND + k + 1) * ND + lane], a3);
    }
    const float x1 = fmaxf(na_b1[lane] + (a0 + a1) + (a2 + a3), 0.f);

    float b0 = 0.f, b1 = 0.f, b2 = 0.f, b3 = 0.f;
#pragma unroll
    for (int k = 0; k < ND; k += 4) {
        b0 = fmaf(rl(x1, k + 0), na_w2[(k + 0) * ND + lane], b0);
        b1 = fmaf(rl(x1, k + 1), na_w2[(k + 1) * ND + lane], b1);
        b2 = fmaf(rl(x1, k + 2), na_w2[(k + 2) * ND + lane], b2);
        b3 = fmaf(rl(x1, k + 3), na_w2[(k + 3) * ND + lane], b3);
    }
    const float x2 = fmaxf(na_b2[lane] + (b0 + b1) + (b2 + b3), 0.f);

    float c0 = 0.f, c1 = 0.f, c2 = 0.f, c3 = 0.f;
#pragma unroll
    for (int k = 0; k < ND; k += 4) {
        c0 = fmaf(rl(x2, k + 0), na_w3[(k + 0) * ND + lane], c0);
        c1 = fmaf(rl(x2, k + 1), na_w3[(k + 1) * ND + lane], c1);
        c2 = fmaf(rl(x2, k + 2), na_w3[(k + 2) * ND + lane], c2);
        c3 = fmaf(rl(x2, k + 3), na_w3[(k + 3) * ND + lane], c3);
    }
    const float p3 = na_b3[lane] + (c0 + c1) + (c2 + c3);

    const float mean = wave_sum64(p3) * (1.f / 64.f);
    const float dvv = p3 - mean;
    const float var = wave_sum64(dvv * dvv) * (1.f / 64.f);
    const float x3 = dvv * rsqrtf(var + 1e-5f) * na_g[lane] + na_beta[lane];

    out0[row * ND + lane] = nv + x3;
}

extern "C" void kernel_launch(void* const* d_in, const int* in_sizes, int n_in,
                              void* d_out, int out_size, void* d_ws, size_t ws_size,
                              hipStream_t stream) {
    const int*   atom    = (const int*)d_in[0];
    const float* pos     = (const float*)d_in[1];
    const float* mask    = (const float*)d_in[2];
    const float* emb     = (const float*)d_in[3];
    const float* ne_w    = (const float*)d_in[4];
    const float* ne_b    = (const float*)d_in[5];
    const float* ne_g    = (const float*)d_in[6];
    const float* ne_beta = (const float*)d_in[7];
    const float* ee_w1   = (const float*)d_in[8];
    const float* ee_b1   = (const float*)d_in[9];
    const float* ee_w2   = (const float*)d_in[10];
    const float* ee_b2   = (const float*)d_in[11];
    const float* ee_w3   = (const float*)d_in[12];
    const float* ee_b3   = (const float*)d_in[13];
    const float* ee_g    = (const float*)d_in[14];
    const float* ee_beta = (const float*)d_in[15];
    const float* na_w1   = (const float*)d_in[16];
    const float* na_b1   = (const float*)d_in[17];
    const float* na_w2   = (const float*)d_in[18];
    const float* na_b2   = (const float*)d_in[19];
    const float* na_w3   = (const float*)d_in[20];
    const float* na_b3   = (const float*)d_in[21];
    const float* na_g    = (const float*)d_in[22];
    const float* na_beta = (const float*)d_in[23];

    float* out0     = (float*)d_out;                       // (B,N,D)
    float* edge_out = (float*)d_out + NB * NN * ND;        // (B,N,N,E)

    float* ws_node = (float*)d_ws;                         // 131072 f32
    float* ws_s    = ws_node + NB * NN * ND;               // 131072
    float* ws_t    = ws_s + NB * NN * NE;                  // 131072
    float* ws_agg  = ws_t + NB * NN * NE;                  // 131072
    unsigned short* wr_t = (unsigned short*)(ws_agg + NB * NN * NE);  // 2048 u16
    unsigned short* w2t  = wr_t + NE * NR;                 // 4096
    unsigned short* w3t  = w2t + NE * NE;                  // 4096

    hipLaunchKernelGGL(k_prep, dim3(1), dim3(256), 0, stream,
                       ee_w1, ee_w2, ee_w3, wr_t, w2t, w3t);

    hipLaunchKernelGGL(k1_node, dim3(NB * NN / 4), dim3(256), 0, stream,
                       atom, emb, ne_w, ne_b, ne_g, ne_beta, ee_w1, ee_b1,
                       ws_node, ws_s, ws_t);

    hipLaunchKernelGGL(k2_edge, dim3(NB * NN), dim3(256), 0, stream,
                       pos, mask, atom, ws_s, ws_t, wr_t, w2t, w3t,
                       ee_b2, ee_b3, ee_g, ee_beta, edge_out, ws_agg);

    hipLaunchKernelGGL(k3_final, dim3(NB * NN / 4), dim3(256), 0, stream,
                       ws_node, ws_agg, na_w1, na_b1, na_w2, na_b2, na_w3, na_b3,
                       na_g, na_beta, out0);
}